// Round 2
// baseline (4577.052 us; speedup 1.0000x reference)
//
#include <hip/hip_runtime.h>

#define N_SRC 8192
#define N_DST 4096
#define KNBR 64
#define F_IN 64
#define H1 64
#define F_MSG 128
#define F_OUT 128
#define POOLCAP 448
#define NWAVE 16
#define FPS_T 1024
#define PPT 8
#define ENC 0x40000000u
#define ENCRANGE 0x3F800000u

typedef float v2f __attribute__((ext_vector_type(2)));
typedef unsigned long long ull;

// Exact-rounding squared distance, matching numpy's ((dx*dx+dy*dy)+dz*dz)
// with no FMA contraction (argmax/selection must be bit-identical to ref).
__device__ __forceinline__ float d2f(float ax, float ay, float az,
                                     float bx, float by, float bz) {
#pragma clang fp contract(off)
    float dx = ax - bx;
    float dy = ay - by;
    float dz = az - bz;
    return (dx * dx + dy * dy) + dz * dz;
}

__device__ __forceinline__ unsigned rowmax16_u32(unsigned x) {
    // row-of-16 max; lane 15 of each row holds the row max. bound_ctrl=true:
    // OOB sources read 0 — identity for nonneg-float bit patterns.
    x = max(x, (unsigned)__builtin_amdgcn_update_dpp(0, (int)x, 0x111, 0xf, 0xf, true)); // row_shr:1
    x = max(x, (unsigned)__builtin_amdgcn_update_dpp(0, (int)x, 0x112, 0xf, 0xf, true)); // row_shr:2
    x = max(x, (unsigned)__builtin_amdgcn_update_dpp(0, (int)x, 0x114, 0xf, 0xf, true)); // row_shr:4
    x = max(x, (unsigned)__builtin_amdgcn_update_dpp(0, (int)x, 0x118, 0xf, 0xf, true)); // row_shr:8
    return x;
}

__device__ __forceinline__ unsigned wave_max_u32(unsigned x) {
    x = rowmax16_u32(x);
    x = max(x, (unsigned)__builtin_amdgcn_update_dpp(0, (int)x, 0x142, 0xf, 0xf, true)); // row_bcast:15
    x = max(x, (unsigned)__builtin_amdgcn_update_dpp(0, (int)x, 0x143, 0xf, 0xf, true)); // row_bcast:31
    return x;  // valid in lane 63
}

__device__ __forceinline__ v2f fmax2(v2f a, v2f b) {
    v2f r;
    r.x = fmaxf(a.x, b.x);
    r.y = fmaxf(a.y, b.y);
    return r;
}

// wave-level ordering fence for per-wave LDS communication
__device__ __forceinline__ void wbar() {
    __asm__ volatile("" ::: "memory");
    __builtin_amdgcn_wave_barrier();
    __asm__ volatile("" ::: "memory");
}

struct FpsSh {
    // double-buffered per-wave argmax records {x,y,z, d2bits-as-float};
    // parity i&1 -> iter i+2's overwrite is separated from iter i's readers
    // by barrier i+1 (single barrier per iteration, no race).
    __align__(16) float4 rec[2][16];
};
struct WkSh {
    float w1s[67 * 64];
    float w2s[64 * 128];
    ull pool[NWAVE][POOLCAP];
    __align__(16) float msgx[NWAVE][64];
    float rel3[NWAVE][4];
    __align__(16) float h1s[NWAVE][64];
    __align__(16) float aggs[NWAVE][128];
    unsigned cnts[NWAVE];
};
union SharedU {
    FpsSh fps;
    WkSh wk;
};

// ---------------------------------------------------------------------------
// FPS body (block 0) — 16 working waves, PPT=8 (the proven 52-VGPR config),
// restructured to ONE barrier per iteration:
//   pre-barrier : each wave extracts its own argmax record {x,y,z,bits}
//                 (wave-max DPP -> readlane -> ballot/ffs -> single-lane
//                 k-scan, tie-break logic verbatim) and posts it to
//                 rec[i&1][w].
//   barrier     : __syncthreads (the only one).
//   post-barrier: lane reads rec[lane&15] (4 replicated rows), rowmax16 DPP
//                 gives the global max, ballot/ffs picks the LOWEST wave
//                 holding it (= lowest global index: wave is the high field
//                 of p = t*8+j), then one broadcast b128 read of the winner
//                 record yields q for all lanes.
// This deletes the old B2 barrier and one dependent LDS round-trip from the
// serial chain. Publish protocol unchanged: plain stores to pos_dst (host
// consumer) + relaxed agent-scope ENCODED stores to staging (device).
// ---------------------------------------------------------------------------
__device__ void fps_body(const float* __restrict__ pos,
                         float* __restrict__ pos_dst,
                         unsigned* __restrict__ stage, FpsSh* sh) {
    const int t = threadIdx.x;
    const int lane = t & 63;
    const int w = t >> 6;

    v2f px2[4], py2[4], pz2[4], d2[4];
    const float x0 = pos[0], y0 = pos[1], z0 = pos[2];
    v2f bm = (v2f){0.0f, 0.0f};
#pragma unroll
    for (int k = 0; k < 4; k++) {
        int p = t * PPT + 2 * k;
        float ax = pos[3 * p], ay = pos[3 * p + 1], az = pos[3 * p + 2];
        float bx = pos[3 * p + 3], by = pos[3 * p + 4], bz = pos[3 * p + 5];
        px2[k] = (v2f){ax, bx};
        py2[k] = (v2f){ay, by};
        pz2[k] = (v2f){az, bz};
        v2f dd;
        dd.x = d2f(ax, ay, az, x0, y0, z0);
        dd.y = d2f(bx, by, bz, x0, y0, z0);
        d2[k] = dd;
        bm = fmax2(bm, dd);
    }
    unsigned bv = __float_as_uint(fmaxf(bm.x, bm.y));

    // pos_dst register window (wave 0): lane l holds sample 64m+l.
    // Lane 0 seeded with sample 0 (flushed at i=63 covering rows 0..63).
    float sx = x0, sy = y0, sz = z0;

    for (int i = 1; i < N_DST; i++) {
        // ---- pre-barrier: per-wave argmax record ----
        {
            unsigned wm = wave_max_u32(bv);
            const unsigned wms = (unsigned)__builtin_amdgcn_readlane((int)wm, 63);
            const ull mask = __ballot(bv == wms);
            const int first = __ffsll(mask) - 1;  // lowest lane == lowest idx
            if (lane == first) {
                int bp = 0;
#pragma unroll
                for (int k = 3; k >= 0; k--) {
                    if (__float_as_uint(d2[k].y) == wms) bp = 2 * k + 1;
                    if (__float_as_uint(d2[k].x) == wms) bp = 2 * k;
                }
                float bx = px2[0].x, by = py2[0].x, bz = pz2[0].x;
#pragma unroll
                for (int k = 0; k < 4; k++) {
                    if (bp == 2 * k)     { bx = px2[k].x; by = py2[k].x; bz = pz2[k].x; }
                    if (bp == 2 * k + 1) { bx = px2[k].y; by = py2[k].y; bz = pz2[k].y; }
                }
                sh->rec[i & 1][w] =
                    make_float4(bx, by, bz, __uint_as_float(wms));
            }
        }
        __syncthreads();  // the ONLY barrier per iteration

        // ---- post-barrier: global winner (all waves, uniform) ----
        const float4 r4 = sh->rec[i & 1][lane & 15];
        const unsigned rb = __float_as_uint(r4.w);
        unsigned m = rowmax16_u32(rb);
        const unsigned gmax = (unsigned)__builtin_amdgcn_readlane((int)m, 15);
        const ull wmask = __ballot(rb == gmax);
        const int ww = __ffsll(wmask) - 1;  // lowest wave == exact tie-break
        const float4 q4 = sh->rec[i & 1][ww];  // uniform broadcast b128
        const float qx = q4.x, qy = q4.y, qz = q4.z;

        if (w == 0) {
            if ((i & 63) == lane) { sx = qx; sy = qy; sz = qz; }
            if ((i & 63) == 63) {
                int b = i - 63 + lane;
                // output copy (host-only consumer): plain fire-and-forget
                pos_dst[3 * b] = sx;
                pos_dst[3 * b + 1] = sy;
                pos_dst[3 * b + 2] = sz;
                // staging copy (device consumers): encoded, uncached, relaxed
                __hip_atomic_store(&stage[3 * b], __float_as_uint(sx) + ENC,
                                   __ATOMIC_RELAXED, __HIP_MEMORY_SCOPE_AGENT);
                __hip_atomic_store(&stage[3 * b + 1], __float_as_uint(sy) + ENC,
                                   __ATOMIC_RELAXED, __HIP_MEMORY_SCOPE_AGENT);
                __hip_atomic_store(&stage[3 * b + 2], __float_as_uint(sz) + ENC,
                                   __ATOMIC_RELAXED, __HIP_MEMORY_SCOPE_AGENT);
            }
        }
        if (i == N_DST - 1) break;

        const v2f qxv = (v2f){qx, qx};
        const v2f qyv = (v2f){qy, qy};
        const v2f qzv = (v2f){qz, qz};
        v2f nbm = (v2f){0.0f, 0.0f};
#pragma unroll
        for (int k = 0; k < 4; k++) {
#pragma clang fp contract(off)
            v2f dx = px2[k] - qxv;
            v2f dy = py2[k] - qyv;
            v2f dz = pz2[k] - qzv;
            v2f dd = (dx * dx + dy * dy) + dz * dz;
            v2f cur = d2[k];
            v2f mn;
            mn.x = fminf(cur.x, dd.x);
            mn.y = fminf(cur.y, dd.y);
            d2[k] = mn;
            nbm = fmax2(nbm, mn);
        }
        bv = __float_as_uint(fmaxf(nbm.x, nbm.y));
    }
}

// ---------------------------------------------------------------------------
// Worker row: poll own row's 3 staging words (relaxed uncached loads) until
// all decode into the valid encoded range, then ball-query nearest-64 within
// r (exact keys + tie-break), PointConv MLP + masked max + global linear.
// ---------------------------------------------------------------------------
__device__ void do_row(int r, int w, int lane, SharedU* sh,
                       const float* __restrict__ x,
                       const float* __restrict__ pos,
                       const unsigned* __restrict__ stage,
                       const float* __restrict__ wg, float* __restrict__ y,
                       float bb1, float bb2a, float bb2b, float bg0,
                       float bg1) {
    unsigned u0, u1, u2;
    for (;;) {
        u0 = __hip_atomic_load(&stage[3 * r], __ATOMIC_RELAXED,
                               __HIP_MEMORY_SCOPE_AGENT);
        u1 = __hip_atomic_load(&stage[3 * r + 1], __ATOMIC_RELAXED,
                               __HIP_MEMORY_SCOPE_AGENT);
        u2 = __hip_atomic_load(&stage[3 * r + 2], __ATOMIC_RELAXED,
                               __HIP_MEMORY_SCOPE_AGENT);
        if ((u0 - ENC) < ENCRANGE && (u1 - ENC) < ENCRANGE &&
            (u2 - ENC) < ENCRANGE)
            break;
        __builtin_amdgcn_s_sleep(32);
    }
    const float qx = __uint_as_float(u0 - ENC);
    const float qy = __uint_as_float(u1 - ENC);
    const float qz = __uint_as_float(u2 - ENC);
    // threshold: f32 nearest of (double)0.2*0.2 -> 0.039999999105930328f
    const float R2 = (float)(0.2 * 0.2);

    if (lane == 0) sh->wk.cnts[w] = 0;
    wbar();
    for (int p = lane; p < N_SRC; p += 64) {
        float d2 = d2f(pos[3 * p], pos[3 * p + 1], pos[3 * p + 2], qx, qy, qz);
        if (d2 <= R2) {
            unsigned s = atomicAdd(&sh->wk.cnts[w], 1u);
            if (s < POOLCAP)
                sh->wk.pool[w][s] =
                    (((ull)__float_as_uint(d2)) << 13) | (ull)(unsigned)p;
        }
    }
    wbar();
    int cnt = (int)sh->wk.cnts[w];
    if (cnt > POOLCAP) cnt = POOLCAP;
    const int nsel = cnt < KNBR ? cnt : KNBR;

    int my_nbr = 0;  // default for unused slots (guarded by cnt below)
    for (int step = 0; step < nsel; step++) {
        ull best = ~0ull;
        int bs = -1;
        for (int s = lane; s < cnt; s += 64) {
            ull k = sh->wk.pool[w][s];
            if (k < best) { best = k; bs = s; }
        }
        const ull lbest = best;
#pragma unroll
        for (int off = 1; off < 64; off <<= 1) {
            ull o = __shfl_xor(best, off);
            if (o < best) best = o;
        }
        if (bs >= 0 && lbest == best) sh->wk.pool[w][bs] = ~0ull;  // unique owner
        if (lane == step) my_nbr = (int)(best & 8191ull);
    }
    wbar();

    float agg0 = -1e30f, agg1 = -1e30f;

    for (int j = 0; j < KNBR + 1; j++) {
        const bool valid = (j < cnt) || (j == KNBR);
        const int src = (j == KNBR) ? r : ((j < cnt) ? __shfl(my_nbr, j) : 0);

        sh->wk.msgx[w][lane] = x[src * F_IN + lane];
        if (lane < 3) {
            float pv = (lane == 0) ? qx : ((lane == 1) ? qy : qz);
            sh->wk.rel3[w][lane] = pos[3 * src + lane] - pv;
        }
        wbar();

        // h1[lane] = relu(b1 + msg . w1[:,lane])
        float a = bb1;
        const float4* m4 = (const float4*)sh->wk.msgx[w];
#pragma unroll
        for (int k4 = 0; k4 < 16; k4++) {
            float4 mm = m4[k4];
            int k = k4 * 4;
            a += mm.x * sh->wk.w1s[k * 64 + lane];
            a += mm.y * sh->wk.w1s[(k + 1) * 64 + lane];
            a += mm.z * sh->wk.w1s[(k + 2) * 64 + lane];
            a += mm.w * sh->wk.w1s[(k + 3) * 64 + lane];
        }
        a += sh->wk.rel3[w][0] * sh->wk.w1s[64 * 64 + lane];
        a += sh->wk.rel3[w][1] * sh->wk.w1s[65 * 64 + lane];
        a += sh->wk.rel3[w][2] * sh->wk.w1s[66 * 64 + lane];
        sh->wk.h1s[w][lane] = fmaxf(a, 0.0f);
        wbar();

        // h2[m] for m = lane, lane+64
        float acc0 = bb2a, acc1 = bb2b;
        const float4* h4 = (const float4*)sh->wk.h1s[w];
#pragma unroll
        for (int k4 = 0; k4 < 16; k4++) {
            float4 h = h4[k4];
            int k = k4 * 4;
            acc0 += h.x * sh->wk.w2s[k * 128 + lane];
            acc1 += h.x * sh->wk.w2s[k * 128 + 64 + lane];
            acc0 += h.y * sh->wk.w2s[(k + 1) * 128 + lane];
            acc1 += h.y * sh->wk.w2s[(k + 1) * 128 + 64 + lane];
            acc0 += h.z * sh->wk.w2s[(k + 2) * 128 + lane];
            acc1 += h.z * sh->wk.w2s[(k + 2) * 128 + 64 + lane];
            acc0 += h.w * sh->wk.w2s[(k + 3) * 128 + lane];
            acc1 += h.w * sh->wk.w2s[(k + 3) * 128 + 64 + lane];
        }
        if (valid) {
            agg0 = fmaxf(agg0, acc0);
            agg1 = fmaxf(agg1, acc1);
        }
        wbar();
    }

    sh->wk.aggs[w][lane] = agg0;
    sh->wk.aggs[w][64 + lane] = agg1;
    wbar();

    // y[m] = bg[m] + agg . wg[:,m], m = lane, lane+64 (wg via L2, coalesced)
    float y0 = bg0, y1 = bg1;
    const float4* a4 = (const float4*)sh->wk.aggs[w];
#pragma unroll
    for (int k4 = 0; k4 < 32; k4++) {
        float4 av = a4[k4];
        int k = k4 * 4;
        y0 += av.x * wg[k * 128 + lane];
        y1 += av.x * wg[k * 128 + 64 + lane];
        y0 += av.y * wg[(k + 1) * 128 + lane];
        y1 += av.y * wg[(k + 1) * 128 + 64 + lane];
        y0 += av.z * wg[(k + 2) * 128 + lane];
        y1 += av.z * wg[(k + 2) * 128 + 64 + lane];
        y0 += av.w * wg[(k + 3) * 128 + lane];
        y1 += av.w * wg[(k + 3) * 128 + 64 + lane];
    }
    y[r * F_OUT + lane] = y0;
    y[r * F_OUT + 64 + lane] = y1;
}

// ---------------------------------------------------------------------------
// Fused kernel: 256 blocks x 1024 threads. LDS ~124 KB => exactly 1 block/CU
// => all 256 blocks co-resident under any dispatch order (deadlock-free).
// Block 0: FPS producer. Blocks 1..255: EPOCH-INTERLEAVED mapping —
// row = w*255 + (bid-1): each block's 16 waves own rows spread evenly across
// publish epochs (work hides under FPS; no per-CU backlog), and the rows of
// the FINAL flush land on ~64 distinct CUs, one wave each (tail = one row).
// Leftover rows 4080..4095 go one-each to wave 15 of blocks 2..17.
// ---------------------------------------------------------------------------
__global__ __launch_bounds__(FPS_T) void fused_kernel(
    const float* __restrict__ x, const float* __restrict__ pos,
    const float* __restrict__ w1, const float* __restrict__ b1,
    const float* __restrict__ w2, const float* __restrict__ b2,
    const float* __restrict__ wg, const float* __restrict__ bg,
    float* __restrict__ y, float* __restrict__ pos_dst,
    unsigned* __restrict__ stage) {
    __shared__ SharedU sh;

    const int bid = blockIdx.x;
    const int t = threadIdx.x;
    const int lane = t & 63;
    const int w = t >> 6;

    if (bid == 0) {
        fps_body(pos, pos_dst, stage, &sh.fps);
        return;
    }

    // stage weights (all 1024 threads)
    for (int i = t; i < 67 * 64; i += 1024) sh.wk.w1s[i] = w1[i];
    for (int i = t; i < 64 * 128; i += 1024) sh.wk.w2s[i] = w2[i];
    __syncthreads();

    const float bb1 = b1[lane];
    const float bb2a = b2[lane];
    const float bb2b = b2[64 + lane];
    const float bg0 = bg[lane];
    const float bg1 = bg[64 + lane];

    const int row = w * 255 + (bid - 1);  // rows 0..4079, epoch-interleaved
    do_row(row, w, lane, &sh, x, pos, stage, wg, y, bb1, bb2a, bb2b, bg0, bg1);
    if (w == 15 && bid >= 2 && bid <= 17)  // rows 4080..4095, one per block
        do_row(4080 + (bid - 2), w, lane, &sh, x, pos, stage, wg, y, bb1,
               bb2a, bb2b, bg0, bg1);
}

extern "C" void kernel_launch(void* const* d_in, const int* in_sizes, int n_in,
                              void* d_out, int out_size, void* d_ws,
                              size_t ws_size, hipStream_t stream) {
    const float* x   = (const float*)d_in[0];  // [8192,64]
    const float* pos = (const float*)d_in[1];  // [8192,3]
    const float* w1  = (const float*)d_in[2];  // [67,64]
    const float* b1  = (const float*)d_in[3];  // [64]
    const float* w2  = (const float*)d_in[4];  // [64,128]
    const float* b2  = (const float*)d_in[5];  // [128]
    const float* wg  = (const float*)d_in[6];  // [128,128]
    const float* bg  = (const float*)d_in[7];  // [128]
    // d_in[8] = training (always 1 -> K=64)

    float* y = (float*)d_out;            // [4096,128]
    float* pos_dst = y + N_DST * F_OUT;  // [4096,3]
    unsigned* stage = (unsigned*)d_ws;   // [4096,3] encoded staging

    fused_kernel<<<256, FPS_T, 0, stream>>>(x, pos, w1, b1, w2, b2, wg, bg, y,
                                            pos_dst, stage);
}

// Round 4
// 3612.772 us; speedup vs baseline: 1.2669x; 1.2669x over previous
//
#include <hip/hip_runtime.h>

#define N_SRC 8192
#define N_DST 4096
#define KNBR 64
#define F_IN 64
#define H1 64
#define F_MSG 128
#define F_OUT 128
#define POOLCAP 448
#define NWAVE 16
#define FPS_T 1024
#define PPT 8
#define ENC 0x40000000u
#define ENCRANGE 0x3F800000u

typedef float v2f __attribute__((ext_vector_type(2)));
typedef unsigned long long ull;

// Exact-rounding squared distance, matching numpy's ((dx*dx+dy*dy)+dz*dz)
// with no FMA contraction (argmax/selection must be bit-identical to ref).
__device__ __forceinline__ float d2f(float ax, float ay, float az,
                                     float bx, float by, float bz) {
#pragma clang fp contract(off)
    float dx = ax - bx;
    float dy = ay - by;
    float dz = az - bz;
    return (dx * dx + dy * dy) + dz * dz;
}

__device__ __forceinline__ unsigned rowmax16_u32(unsigned x) {
    // row-of-16 max; lane 15 of each row holds the row max. bound_ctrl=true:
    // OOB sources read 0 — identity for nonneg-float bit patterns.
    x = max(x, (unsigned)__builtin_amdgcn_update_dpp(0, (int)x, 0x111, 0xf, 0xf, true)); // row_shr:1
    x = max(x, (unsigned)__builtin_amdgcn_update_dpp(0, (int)x, 0x112, 0xf, 0xf, true)); // row_shr:2
    x = max(x, (unsigned)__builtin_amdgcn_update_dpp(0, (int)x, 0x114, 0xf, 0xf, true)); // row_shr:4
    x = max(x, (unsigned)__builtin_amdgcn_update_dpp(0, (int)x, 0x118, 0xf, 0xf, true)); // row_shr:8
    return x;
}

__device__ __forceinline__ unsigned wave_max_u32(unsigned x) {
    x = rowmax16_u32(x);
    x = max(x, (unsigned)__builtin_amdgcn_update_dpp(0, (int)x, 0x142, 0xf, 0xf, true)); // row_bcast:15
    x = max(x, (unsigned)__builtin_amdgcn_update_dpp(0, (int)x, 0x143, 0xf, 0xf, true)); // row_bcast:31
    return x;  // valid in lane 63
}

__device__ __forceinline__ v2f fmax2(v2f a, v2f b) {
    v2f r;
    r.x = fmaxf(a.x, b.x);
    r.y = fmaxf(a.y, b.y);
    return r;
}

// wave-level ordering fence for per-wave LDS communication
__device__ __forceinline__ void wbar() {
    __asm__ volatile("" ::: "memory");
    __builtin_amdgcn_wave_barrier();
    __asm__ volatile("" ::: "memory");
}

// Lean block barrier for the FPS loop: orders LDS only (lgkmcnt), skips the
// vmcnt(0) drain __syncthreads would emit. Safe here: the only vmem in the
// steady loop is wave 0's fire-and-forget publish stores, which no barrier
// consumer orders on (device consumers validate by encode-range). Uses the
// compiler-visible builtin barrier (scheduler knows it's a barrier) with an
// explicit asm waitcnt — the guide's verified 8-phase idiom.
__device__ __forceinline__ void fbar() {
    __asm__ volatile("s_waitcnt lgkmcnt(0)" ::: "memory");
    __builtin_amdgcn_s_barrier();
}

struct FpsSh {
    unsigned wmaxS[16];
    __align__(16) float qS[4];
};
struct WkSh {
    float w1s[67 * 64];
    float w2s[64 * 128];
    ull pool[NWAVE][POOLCAP];
    __align__(16) float msgx[NWAVE][64];
    float rel3[NWAVE][4];
    __align__(16) float h1s[NWAVE][64];
    __align__(16) float aggs[NWAVE][128];
    unsigned cnts[NWAVE];
};
union SharedU {
    FpsSh fps;
    WkSh wk;
};

// ---------------------------------------------------------------------------
// FPS body (block 0) — R0's proven two-barrier protocol (16 waves, PPT=8,
// cheap all-wave phases; expensive scan confined to the winner wave), with
// three protocol-free cuts:
//  * lean barriers (no vmcnt drain) at B1/B2
//  * post-loop max3 tree for the lane max (replaces in-loop accumulation)
//  * fused winner scan: direct descending-k coordinate select (8 cmp +
//    24 cndmask), same lowest-index tie-break (lower k overwrites, .x
//    checked after .y so the even/lower element wins).
// Publish protocol unchanged: plain stores to pos_dst (host consumer) +
// relaxed agent-scope ENCODED stores to staging (device consumers).
// ---------------------------------------------------------------------------
__device__ void fps_body(const float* __restrict__ pos,
                         float* __restrict__ pos_dst,
                         unsigned* __restrict__ stage, FpsSh* sh) {
    const int t = threadIdx.x;
    const int lane = t & 63;
    const int w = t >> 6;

    v2f px2[4], py2[4], pz2[4], d2[4];
    const float x0 = pos[0], y0 = pos[1], z0 = pos[2];
    v2f bm = (v2f){0.0f, 0.0f};
#pragma unroll
    for (int k = 0; k < 4; k++) {
        int p = t * PPT + 2 * k;
        float ax = pos[3 * p], ay = pos[3 * p + 1], az = pos[3 * p + 2];
        float bx = pos[3 * p + 3], by = pos[3 * p + 4], bz = pos[3 * p + 5];
        px2[k] = (v2f){ax, bx};
        py2[k] = (v2f){ay, by};
        pz2[k] = (v2f){az, bz};
        v2f dd;
        dd.x = d2f(ax, ay, az, x0, y0, z0);
        dd.y = d2f(bx, by, bz, x0, y0, z0);
        d2[k] = dd;
        bm = fmax2(bm, dd);
    }
    unsigned bv = __float_as_uint(fmaxf(bm.x, bm.y));

    // pos_dst register window (wave 0): lane l holds sample 64m+l.
    // Lane 0 seeded with sample 0 (flushed at i=63 covering rows 0..63).
    float sx = x0, sy = y0, sz = z0;

    for (int i = 1; i < N_DST; i++) {
        {
            unsigned wm = wave_max_u32(bv);
            if (lane == 63) sh->wmaxS[w] = wm;
        }
        fbar();  // B1

        unsigned v = sh->wmaxS[lane & 15];
        unsigned m = rowmax16_u32(v);
        const unsigned gmax = (unsigned)__builtin_amdgcn_readlane((int)m, 15);
        const ull slotmask = __ballot(v == gmax) & 0xffffull;
        const int ww = __ffsll(slotmask) - 1;  // lowest wave == exact tie-break

        if (w == ww) {
            const ull mask = __ballot(bv == gmax);
            const int first = __ffsll(mask) - 1;  // lowest lane == lowest idx
            if (lane == first) {
                // direct descending-k select: lower k overwrites, .x after .y
                // => lowest original index wins among equal keys.
                float bx = px2[0].x, by = py2[0].x, bz = pz2[0].x;
#pragma unroll
                for (int k = 3; k >= 0; k--) {
                    if (__float_as_uint(d2[k].y) == gmax) {
                        bx = px2[k].y; by = py2[k].y; bz = pz2[k].y;
                    }
                    if (__float_as_uint(d2[k].x) == gmax) {
                        bx = px2[k].x; by = py2[k].x; bz = pz2[k].x;
                    }
                }
                *(float4*)sh->qS = make_float4(bx, by, bz, 0.0f);
            }
        }
        fbar();  // B2

        const float4 q4 = *(const float4*)sh->qS;  // broadcast b128
        const float qx = q4.x, qy = q4.y, qz = q4.z;

        if (w == 0) {
            if ((i & 63) == lane) { sx = qx; sy = qy; sz = qz; }
            if ((i & 63) == 63) {
                int b = i - 63 + lane;
                // output copy (host-only consumer): plain fire-and-forget
                pos_dst[3 * b] = sx;
                pos_dst[3 * b + 1] = sy;
                pos_dst[3 * b + 2] = sz;
                // staging copy (device consumers): encoded, uncached, relaxed
                __hip_atomic_store(&stage[3 * b], __float_as_uint(sx) + ENC,
                                   __ATOMIC_RELAXED, __HIP_MEMORY_SCOPE_AGENT);
                __hip_atomic_store(&stage[3 * b + 1], __float_as_uint(sy) + ENC,
                                   __ATOMIC_RELAXED, __HIP_MEMORY_SCOPE_AGENT);
                __hip_atomic_store(&stage[3 * b + 2], __float_as_uint(sz) + ENC,
                                   __ATOMIC_RELAXED, __HIP_MEMORY_SCOPE_AGENT);
            }
        }
        if (i == N_DST - 1) break;

        const v2f qxv = (v2f){qx, qx};
        const v2f qyv = (v2f){qy, qy};
        const v2f qzv = (v2f){qz, qz};
#pragma unroll
        for (int k = 0; k < 4; k++) {
#pragma clang fp contract(off)
            v2f dx = px2[k] - qxv;
            v2f dy = py2[k] - qyv;
            v2f dz = pz2[k] - qzv;
            v2f dd = (dx * dx + dy * dy) + dz * dz;
            v2f cur = d2[k];
            v2f mn;
            mn.x = fminf(cur.x, dd.x);
            mn.y = fminf(cur.y, dd.y);
            d2[k] = mn;
        }
        // lane max via max3 tree (4 insts) instead of in-loop accumulation
        float t0 = fmaxf(fmaxf(d2[0].x, d2[0].y), d2[1].x);
        float t1 = fmaxf(fmaxf(d2[1].y, d2[2].x), d2[2].y);
        float t2 = fmaxf(fmaxf(d2[3].x, d2[3].y), t0);
        bv = __float_as_uint(fmaxf(t1, t2));
    }
}

// ---------------------------------------------------------------------------
// Worker row: poll own row's 3 staging words (relaxed uncached loads) until
// all decode into the valid encoded range, then ball-query nearest-64 within
// r (exact keys + tie-break), PointConv MLP + masked max + global linear.
// ---------------------------------------------------------------------------
__device__ void do_row(int r, int w, int lane, SharedU* sh,
                       const float* __restrict__ x,
                       const float* __restrict__ pos,
                       const unsigned* __restrict__ stage,
                       const float* __restrict__ wg, float* __restrict__ y,
                       float bb1, float bb2a, float bb2b, float bg0,
                       float bg1) {
    unsigned u0, u1, u2;
    for (;;) {
        u0 = __hip_atomic_load(&stage[3 * r], __ATOMIC_RELAXED,
                               __HIP_MEMORY_SCOPE_AGENT);
        u1 = __hip_atomic_load(&stage[3 * r + 1], __ATOMIC_RELAXED,
                               __HIP_MEMORY_SCOPE_AGENT);
        u2 = __hip_atomic_load(&stage[3 * r + 2], __ATOMIC_RELAXED,
                               __HIP_MEMORY_SCOPE_AGENT);
        if ((u0 - ENC) < ENCRANGE && (u1 - ENC) < ENCRANGE &&
            (u2 - ENC) < ENCRANGE)
            break;
        __builtin_amdgcn_s_sleep(32);
    }
    const float qx = __uint_as_float(u0 - ENC);
    const float qy = __uint_as_float(u1 - ENC);
    const float qz = __uint_as_float(u2 - ENC);
    // threshold: f32 nearest of (double)0.2*0.2 -> 0.039999999105930328f
    const float R2 = (float)(0.2 * 0.2);

    if (lane == 0) sh->wk.cnts[w] = 0;
    wbar();
    for (int p = lane; p < N_SRC; p += 64) {
        float d2 = d2f(pos[3 * p], pos[3 * p + 1], pos[3 * p + 2], qx, qy, qz);
        if (d2 <= R2) {
            unsigned s = atomicAdd(&sh->wk.cnts[w], 1u);
            if (s < POOLCAP)
                sh->wk.pool[w][s] =
                    (((ull)__float_as_uint(d2)) << 13) | (ull)(unsigned)p;
        }
    }
    wbar();
    int cnt = (int)sh->wk.cnts[w];
    if (cnt > POOLCAP) cnt = POOLCAP;
    const int nsel = cnt < KNBR ? cnt : KNBR;

    int my_nbr = 0;  // default for unused slots (guarded by cnt below)
    for (int step = 0; step < nsel; step++) {
        ull best = ~0ull;
        int bs = -1;
        for (int s = lane; s < cnt; s += 64) {
            ull k = sh->wk.pool[w][s];
            if (k < best) { best = k; bs = s; }
        }
        const ull lbest = best;
#pragma unroll
        for (int off = 1; off < 64; off <<= 1) {
            ull o = __shfl_xor(best, off);
            if (o < best) best = o;
        }
        if (bs >= 0 && lbest == best) sh->wk.pool[w][bs] = ~0ull;  // unique owner
        if (lane == step) my_nbr = (int)(best & 8191ull);
    }
    wbar();

    float agg0 = -1e30f, agg1 = -1e30f;

    for (int j = 0; j < KNBR + 1; j++) {
        const bool valid = (j < cnt) || (j == KNBR);
        const int src = (j == KNBR) ? r : ((j < cnt) ? __shfl(my_nbr, j) : 0);

        sh->wk.msgx[w][lane] = x[src * F_IN + lane];
        if (lane < 3) {
            float pv = (lane == 0) ? qx : ((lane == 1) ? qy : qz);
            sh->wk.rel3[w][lane] = pos[3 * src + lane] - pv;
        }
        wbar();

        // h1[lane] = relu(b1 + msg . w1[:,lane])
        float a = bb1;
        const float4* m4 = (const float4*)sh->wk.msgx[w];
#pragma unroll
        for (int k4 = 0; k4 < 16; k4++) {
            float4 mm = m4[k4];
            int k = k4 * 4;
            a += mm.x * sh->wk.w1s[k * 64 + lane];
            a += mm.y * sh->wk.w1s[(k + 1) * 64 + lane];
            a += mm.z * sh->wk.w1s[(k + 2) * 64 + lane];
            a += mm.w * sh->wk.w1s[(k + 3) * 64 + lane];
        }
        a += sh->wk.rel3[w][0] * sh->wk.w1s[64 * 64 + lane];
        a += sh->wk.rel3[w][1] * sh->wk.w1s[65 * 64 + lane];
        a += sh->wk.rel3[w][2] * sh->wk.w1s[66 * 64 + lane];
        sh->wk.h1s[w][lane] = fmaxf(a, 0.0f);
        wbar();

        // h2[m] for m = lane, lane+64
        float acc0 = bb2a, acc1 = bb2b;
        const float4* h4 = (const float4*)sh->wk.h1s[w];
#pragma unroll
        for (int k4 = 0; k4 < 16; k4++) {
            float4 h = h4[k4];
            int k = k4 * 4;
            acc0 += h.x * sh->wk.w2s[k * 128 + lane];
            acc1 += h.x * sh->wk.w2s[k * 128 + 64 + lane];
            acc0 += h.y * sh->wk.w2s[(k + 1) * 128 + lane];
            acc1 += h.y * sh->wk.w2s[(k + 1) * 128 + 64 + lane];
            acc0 += h.z * sh->wk.w2s[(k + 2) * 128 + lane];
            acc1 += h.z * sh->wk.w2s[(k + 2) * 128 + 64 + lane];
            acc0 += h.w * sh->wk.w2s[(k + 3) * 128 + lane];
            acc1 += h.w * sh->wk.w2s[(k + 3) * 128 + 64 + lane];
        }
        if (valid) {
            agg0 = fmaxf(agg0, acc0);
            agg1 = fmaxf(agg1, acc1);
        }
        wbar();
    }

    sh->wk.aggs[w][lane] = agg0;
    sh->wk.aggs[w][64 + lane] = agg1;
    wbar();

    // y[m] = bg[m] + agg . wg[:,m], m = lane, lane+64 (wg via L2, coalesced)
    float y0 = bg0, y1 = bg1;
    const float4* a4 = (const float4*)sh->wk.aggs[w];
#pragma unroll
    for (int k4 = 0; k4 < 32; k4++) {
        float4 av = a4[k4];
        int k = k4 * 4;
        y0 += av.x * wg[k * 128 + lane];
        y1 += av.x * wg[k * 128 + 64 + lane];
        y0 += av.y * wg[(k + 1) * 128 + lane];
        y1 += av.y * wg[(k + 1) * 128 + 64 + lane];
        y0 += av.z * wg[(k + 2) * 128 + lane];
        y1 += av.z * wg[(k + 2) * 128 + 64 + lane];
        y0 += av.w * wg[(k + 3) * 128 + lane];
        y1 += av.w * wg[(k + 3) * 128 + 64 + lane];
    }
    y[r * F_OUT + lane] = y0;
    y[r * F_OUT + 64 + lane] = y1;
}

// ---------------------------------------------------------------------------
// Fused kernel: 256 blocks x 1024 threads. LDS ~124 KB => exactly 1 block/CU
// => all 256 blocks co-resident under any dispatch order (deadlock-free).
// Block 0: FPS producer. Blocks 1..255: EPOCH-INTERLEAVED mapping —
// row = w*255 + (bid-1): each block's 16 waves own rows spread evenly across
// publish epochs (work hides under FPS; no per-CU backlog), and the rows of
// the FINAL flush land on ~64 distinct CUs, one wave each (tail = one row).
// Leftover rows 4080..4095 go one-each to wave 15 of blocks 2..17.
// ---------------------------------------------------------------------------
__global__ __launch_bounds__(FPS_T) void fused_kernel(
    const float* __restrict__ x, const float* __restrict__ pos,
    const float* __restrict__ w1, const float* __restrict__ b1,
    const float* __restrict__ w2, const float* __restrict__ b2,
    const float* __restrict__ wg, const float* __restrict__ bg,
    float* __restrict__ y, float* __restrict__ pos_dst,
    unsigned* __restrict__ stage) {
    __shared__ SharedU sh;

    const int bid = blockIdx.x;
    const int t = threadIdx.x;
    const int lane = t & 63;
    const int w = t >> 6;

    if (bid == 0) {
        fps_body(pos, pos_dst, stage, &sh.fps);
        return;
    }

    // stage weights (all 1024 threads)
    for (int i = t; i < 67 * 64; i += 1024) sh.wk.w1s[i] = w1[i];
    for (int i = t; i < 64 * 128; i += 1024) sh.wk.w2s[i] = w2[i];
    __syncthreads();

    const float bb1 = b1[lane];
    const float bb2a = b2[lane];
    const float bb2b = b2[64 + lane];
    const float bg0 = bg[lane];
    const float bg1 = bg[64 + lane];

    const int row = w * 255 + (bid - 1);  // rows 0..4079, epoch-interleaved
    do_row(row, w, lane, &sh, x, pos, stage, wg, y, bb1, bb2a, bb2b, bg0, bg1);
    if (w == 15 && bid >= 2 && bid <= 17)  // rows 4080..4095, one per block
        do_row(4080 + (bid - 2), w, lane, &sh, x, pos, stage, wg, y, bb1,
               bb2a, bb2b, bg0, bg1);
}

extern "C" void kernel_launch(void* const* d_in, const int* in_sizes, int n_in,
                              void* d_out, int out_size, void* d_ws,
                              size_t ws_size, hipStream_t stream) {
    const float* x   = (const float*)d_in[0];  // [8192,64]
    const float* pos = (const float*)d_in[1];  // [8192,3]
    const float* w1  = (const float*)d_in[2];  // [67,64]
    const float* b1  = (const float*)d_in[3];  // [64]
    const float* w2  = (const float*)d_in[4];  // [64,128]
    const float* b2  = (const float*)d_in[5];  // [128]
    const float* wg  = (const float*)d_in[6];  // [128,128]
    const float* bg  = (const float*)d_in[7];  // [128]
    // d_in[8] = training (always 1 -> K=64)

    float* y = (float*)d_out;            // [4096,128]
    float* pos_dst = y + N_DST * F_OUT;  // [4096,3]
    unsigned* stage = (unsigned*)d_ws;   // [4096,3] encoded staging

    fused_kernel<<<256, FPS_T, 0, stream>>>(x, pos, w1, b1, w2, b2, wg, bg, y,
                                            pos_dst, stage);
}